// Round 6
// baseline (666.618 us; speedup 1.0000x reference)
//
#include <hip/hip_runtime.h>
#include <hip/hip_bf16.h>
#include <math.h>

#define NN 100000
#define NE 1600000
#define NBUK 391        // dst >> 8 buckets (256 nodes each), 99999>>8 = 390
#define CHUNK 4096      // edges per bucket_scatter block
#define HCHUNK 4096     // edges per histB block
#define NSLOT 78        // W1:64 + W2:8 + W3:6 fragment slots
#define SRCMASK 0xFFFFF // src in bits [0,20), dst&255 in bits [20,28)

typedef __attribute__((ext_vector_type(8))) short bf8_t;   // 8 bf16 = 4 VGPRs
typedef __attribute__((ext_vector_type(4))) float f4_t;    // 4 fp32 acc
typedef __attribute__((ext_vector_type(8))) unsigned short us8_t;  // 16B

__device__ __forceinline__ ushort f2b(float f) {
  __hip_bfloat16 h = __float2bfloat16(f);  // RNE
  return *(ushort*)&h;
}
__device__ __forceinline__ float b2f(ushort u) {
  return __uint_as_float(((unsigned)u) << 16);
}

// ---------------------------------------------------------------------------
// One-time W fragment swizzle: W[K][N] fp32 -> bf16 in MFMA B-frag order.
// slot = (ks*2+s)*NT + t ; element j of lane = W[ks*64+s*32+(lane>>4)*8+j]
//                                               [t*16+(lane&15)]  (0 if col>=N)
// Layout: W1 slots [0,64) | W2 [64,72) | W3 [72,78). Slot stride 512 ushorts.
// ---------------------------------------------------------------------------
__global__ __launch_bounds__(256) void wconv_kernel(
    const float* __restrict__ W1, const float* __restrict__ W2,
    const float* __restrict__ W3, ushort* __restrict__ out) {
  int g = blockIdx.x * 256 + threadIdx.x;  // slot*64 + lane
  if (g >= NSLOT * 64) return;
  int slot = g >> 6, lane = g & 63;
  const float* W;
  int ks, s, t, N;
  if (slot < 64) {
    W = W1; N = 64; ks = slot >> 3; s = (slot >> 2) & 1; t = slot & 3;
  } else if (slot < 72) {
    int l = slot - 64; W = W2; N = 64; ks = 0; s = (l >> 2) & 1; t = l & 3;
  } else {
    int l = slot - 72; W = W3; N = 40; ks = 0; s = l / 3; t = l % 3;
  }
  int col = t * 16 + (lane & 15);
  int krow = ks * 64 + s * 32 + ((lane >> 4) << 3);
  us8_t o;
#pragma unroll
  for (int j = 0; j < 8; j++)
    o[j] = (col < N) ? f2b(W[(long)(krow + j) * N + col]) : (ushort)0;
  *(us8_t*)&out[(size_t)g * 8] = o;
}

// ---------------------------------------------------------------------------
// Barrier-free direct-fragment MFMA GEMM: Y[M,NCOL] = X[M,KS*64] @ W.
// ---------------------------------------------------------------------------
template <int KS, int NT, int NCOL, bool XF32>
__global__ __launch_bounds__(256) void gemm_direct(
    const void* __restrict__ Xv, const ushort* __restrict__ Wb,
    ushort* __restrict__ Y, int M) {
  const int tid = threadIdx.x;
  const int wave = tid >> 6;
  const int lane = tid & 63;
  const int K = KS * 64;
  const int row0 = blockIdx.x * 64 + wave * 16;
  int arow = row0 + (lane & 15);
  if (arow >= M) arow = M - 1;  // clamp: loads stay valid, epilogue guards
  const int kcol = (lane >> 4) << 3;

  f4_t acc[NT];
#pragma unroll
  for (int t = 0; t < NT; t++) acc[t] = (f4_t){0.f, 0.f, 0.f, 0.f};

#pragma unroll 2
  for (int ks = 0; ks < KS; ks++) {
#pragma unroll
    for (int s = 0; s < 2; s++) {
      const int kbase = ks * 64 + s * 32 + kcol;
      bf8_t af;
      if (XF32) {
        const float* xp = (const float*)Xv + (long)arow * K + kbase;
        float4 a0 = *(const float4*)xp;
        float4 a1 = *(const float4*)(xp + 4);
        af[0] = (short)f2b(a0.x); af[1] = (short)f2b(a0.y);
        af[2] = (short)f2b(a0.z); af[3] = (short)f2b(a0.w);
        af[4] = (short)f2b(a1.x); af[5] = (short)f2b(a1.y);
        af[6] = (short)f2b(a1.z); af[7] = (short)f2b(a1.w);
      } else {
        af = *(const bf8_t*)((const ushort*)Xv + (long)arow * K + kbase);
      }
#pragma unroll
      for (int t = 0; t < NT; t++) {
        bf8_t bf = *(const bf8_t*)&Wb[(size_t)(((ks * 2 + s) * NT + t) * 64 +
                                               lane) * 8];
        acc[t] = __builtin_amdgcn_mfma_f32_16x16x32_bf16(af, bf, acc[t], 0, 0, 0);
      }
    }
  }
  const int crow0 = row0 + ((lane >> 4) << 2);
  const int ccol = lane & 15;
#pragma unroll
  for (int t = 0; t < NT; t++) {
    int col = ccol + t * 16;
    if (col < NCOL) {
#pragma unroll
      for (int r = 0; r < 4; r++) {
        int row = crow0 + r;
        if (row < M) Y[(long)row * NCOL + col] = f2b(acc[t][r]);
      }
    }
  }
}

// ---------------------------------------------------------------------------
// CSR build v3 — near-zero global atomics AND coalesced scatter.
// ---------------------------------------------------------------------------
__global__ __launch_bounds__(256) void histB_kernel(const int* __restrict__ dst,
                                                    int* __restrict__ bkcnt) {
  __shared__ int lh[NBUK];
  const int tid = threadIdx.x;
  for (int i = tid; i < NBUK; i += 256) lh[i] = 0;
  __syncthreads();
  const int q0 = blockIdx.x * (HCHUNK / 4);
#pragma unroll
  for (int k = 0; k < HCHUNK / 1024; k++) {
    int idx = q0 + k * 256 + tid;
    if (idx < NE / 4) {
      int4 d4 = ((const int4*)dst)[idx];
      atomicAdd(&lh[d4.x >> 8], 1);
      atomicAdd(&lh[d4.y >> 8], 1);
      atomicAdd(&lh[d4.z >> 8], 1);
      atomicAdd(&lh[d4.w >> 8], 1);
    }
  }
  __syncthreads();
  for (int i = tid; i < NBUK; i += 256)
    if (lh[i]) atomicAdd(&bkcnt[i], lh[i]);
}

__global__ __launch_bounds__(64) void scan_bkoff_kernel(
    const int* __restrict__ bkcnt, int* __restrict__ bkoff,
    int* __restrict__ bcur) {
  int lane = threadIdx.x;
  int carry = 0;
  for (int base = 0; base < NBUK; base += 64) {
    int i = base + lane;
    int v = (i < NBUK) ? bkcnt[i] : 0;
#pragma unroll
    for (int off = 1; off < 64; off <<= 1) {
      int t = __shfl_up(v, off, 64);
      if (lane >= off) v += t;
    }
    int total = __shfl(v, 63, 64);
    int ex = __shfl_up(v, 1, 64);
    if (lane == 0) ex = 0;
    if (i < NBUK) {
      bkoff[i] = carry + ex;
      bcur[i] = carry + ex;
    }
    carry += total;
  }
  if (lane == 0) bkoff[NBUK] = carry;  // == NE
}

// Pass C: block-local counting sort by bucket, then coalesced run write-out.
__global__ __launch_bounds__(256) void bucket_scatter_kernel(
    const int* __restrict__ src, const int* __restrict__ dst,
    const float* __restrict__ ew, int* __restrict__ bcur,
    int2* __restrict__ esw, int n) {
  __shared__ int lcnt[NBUK];    // counts, then rank cursors
  __shared__ int lofs[NBUK];    // local exclusive scan
  __shared__ int gbase[NBUK];   // reserved global base per bucket
  __shared__ int2 stage[CHUNK]; // 32KB bucket-ordered payload
  __shared__ ushort sbk[CHUNK]; // 8KB bucket id per slot
  const int tid = threadIdx.x;
  const int e0 = blockIdx.x * CHUNK;
  const int n1 = min(CHUNK, n - e0);

  for (int i = tid; i < NBUK; i += 256) lcnt[i] = 0;
  __syncthreads();
  // phase 1: count
#pragma unroll
  for (int k = 0; k < CHUNK / 256; k++) {
    int e = e0 + k * 256 + tid;
    if (e < n) atomicAdd(&lcnt[dst[e] >> 8], 1);
  }
  __syncthreads();
  // phase 2: wave-0 scans lcnt -> lofs (exclusive)
  if (tid < 64) {
    int lane = tid;
    int carry = 0;
    for (int base = 0; base < NBUK; base += 64) {
      int i = base + lane;
      int v = (i < NBUK) ? lcnt[i] : 0;
#pragma unroll
      for (int off = 1; off < 64; off <<= 1) {
        int t = __shfl_up(v, off, 64);
        if (lane >= off) v += t;
      }
      int total = __shfl(v, 63, 64);
      int ex = __shfl_up(v, 1, 64);
      if (lane == 0) ex = 0;
      if (i < NBUK) lofs[i] = carry + ex;
      carry += total;
    }
  }
  __syncthreads();
  // phase 3: reserve global bases; reset counts for rank pass
  for (int i = tid; i < NBUK; i += 256) {
    int c = lcnt[i];
    gbase[i] = c ? atomicAdd(&bcur[i], c) : 0;
    lcnt[i] = 0;
  }
  __syncthreads();
  // phase 4: rank + stage into LDS, bucket-grouped
#pragma unroll
  for (int k = 0; k < CHUNK / 256; k++) {
    int e = e0 + k * 256 + tid;
    if (e < n) {
      int d = dst[e];
      int bk = d >> 8;
      int rk = atomicAdd(&lcnt[bk], 1);
      int slot = lofs[bk] + rk;
      stage[slot] = make_int2(src[e] | ((d & 255) << 20),
                              __float_as_int(ew[e]));
      sbk[slot] = (ushort)bk;
    }
  }
  __syncthreads();
  // phase 5: sequential write-out (runs are contiguous per bucket)
  for (int i = tid; i < n1; i += 256) {
    int bk = sbk[i];
    esw[gbase[bk] + (i - lofs[bk])] = stage[i];
  }
}

// Pass D: block b owns bucket b (256 nodes, ~4K edges). Everything local.
__global__ __launch_bounds__(256) void finalize_kernel(
    const int* __restrict__ bkoff, const int2* __restrict__ esw,
    int* __restrict__ rowptr, int* __restrict__ deg, int2* __restrict__ csr) {
  __shared__ int ldeg[256];
  __shared__ int lcur[256];
  const int b = blockIdx.x;
  const int tid = threadIdx.x;
  const int e0 = bkoff[b], e1 = bkoff[b + 1];

  ldeg[tid] = 0;
  __syncthreads();
  for (int e = e0 + tid; e < e1; e += 256)
    atomicAdd(&ldeg[(esw[e].x >> 20) & 255], 1);
  __syncthreads();
  const int v = ldeg[tid];
  lcur[tid] = v;
  __syncthreads();
#pragma unroll
  for (int off = 1; off < 256; off <<= 1) {
    int t = (tid >= off) ? lcur[tid - off] : 0;
    __syncthreads();
    lcur[tid] += t;
    __syncthreads();
  }
  const int excl = lcur[tid] - v;  // exclusive local prefix
  const int node = b * 256 + tid;
  if (node < NN) {
    rowptr[node] = e0 + excl;
    deg[node] = v;
  }
  __syncthreads();
  lcur[tid] = e0 + excl;  // absolute write cursor for this node
  __syncthreads();
  for (int e = e0 + tid; e < e1; e += 256) {
    int2 x = esw[e];
    int pos = atomicAdd(&lcur[(x.x >> 20) & 255], 1);
    csr[pos] = x;  // stays packed; agg kernels mask with SRCMASK
  }
}

// ---------------------------------------------------------------------------
// Pull aggregation D=64 v2: 16 edges in flight per wave (4 lanes/edge,
// 32B/lane). Avg degree 16 -> whole row's gather issues in ONE latency
// round (1 csr vector load + 16 independent H-row loads in flight).
// ---------------------------------------------------------------------------
template <bool RELU>
__global__ __launch_bounds__(256) void agg64_kernel(
    const int* __restrict__ rowptr, const int* __restrict__ deg,
    const int2* __restrict__ csr, const ushort* __restrict__ H,
    const float* __restrict__ b, ushort* __restrict__ out, int nR) {
  int lane = threadIdx.x & 63;
  int r = blockIdx.x * 4 + (threadIdx.x >> 6);
  if (r >= nR) return;
  int beg = rowptr[r];
  int d = deg[r];
  int g = lane >> 2;   // 16 edge slots
  int sub = lane & 3;  // 32B quarter of the 128B row
  float acc[16];
#pragma unroll
  for (int k = 0; k < 16; k++) acc[k] = 0.f;

  for (int j0 = 0; j0 < d; j0 += 16) {
    int jj = j0 + g;
    int2 cw = (jj < d) ? csr[beg + jj] : make_int2(0, 0);  // w=0 pad
    float w = __int_as_float(cw.y);
    const us8_t* hp =
        (const us8_t*)&H[(long)(cw.x & SRCMASK) * 64 + sub * 16];
    us8_t h0 = hp[0];
    us8_t h1 = hp[1];
#pragma unroll
    for (int k = 0; k < 8; k++) {
      acc[k] += w * b2f(h0[k]);
      acc[8 + k] += w * b2f(h1[k]);
    }
  }
#pragma unroll
  for (int off = 4; off < 64; off <<= 1)
#pragma unroll
    for (int k = 0; k < 16; k++) acc[k] += __shfl_xor(acc[k], off, 64);

  if (g == 0) {
    us8_t o0, o1;
#pragma unroll
    for (int k = 0; k < 8; k++) {
      float v0 = acc[k] + b[sub * 16 + k];
      float v1 = acc[8 + k] + b[sub * 16 + 8 + k];
      if (RELU) {
        v0 = fmaxf(v0, 0.f);
        v1 = fmaxf(v1, 0.f);
      }
      o0[k] = f2b(v0);
      o1[k] = f2b(v1);
    }
    *(us8_t*)&out[(long)r * 64 + sub * 16] = o0;
    *(us8_t*)&out[(long)r * 64 + sub * 16 + 8] = o1;
  }
}

// ---------------------------------------------------------------------------
// Layer-3 fused v2: 16-edges-in-flight aggregation (D=40, 80B rows:
// sub0/1 cover 32B each, sub2 covers 16B, sub3 idle) + bias + log_softmax.
// ---------------------------------------------------------------------------
__global__ __launch_bounds__(256) void agg_lsm_kernel(
    const int* __restrict__ rowptr, const int* __restrict__ deg,
    const int2* __restrict__ csr, const ushort* __restrict__ H,
    const float* __restrict__ b, float* __restrict__ out, int nR) {
  int lane = threadIdx.x & 63;
  int r = blockIdx.x * 4 + (threadIdx.x >> 6);
  if (r >= nR) return;
  int beg = rowptr[r];
  int d = deg[r];
  int g = lane >> 2;
  int sub = lane & 3;
  float acc[16];
#pragma unroll
  for (int k = 0; k < 16; k++) acc[k] = 0.f;

  for (int j0 = 0; j0 < d; j0 += 16) {
    int jj = j0 + g;
    int2 cw = (jj < d) ? csr[beg + jj] : make_int2(0, 0);
    float w = __int_as_float(cw.y);
    const ushort* hp = &H[(long)(cw.x & SRCMASK) * 40 + sub * 16];
    if (sub < 2) {
      us8_t h0 = *(const us8_t*)hp;
      us8_t h1 = *(const us8_t*)(hp + 8);
#pragma unroll
      for (int k = 0; k < 8; k++) {
        acc[k] += w * b2f(h0[k]);
        acc[8 + k] += w * b2f(h1[k]);
      }
    } else if (sub == 2) {
      us8_t h0 = *(const us8_t*)hp;
#pragma unroll
      for (int k = 0; k < 8; k++) acc[k] += w * b2f(h0[k]);
    }
  }
#pragma unroll
  for (int off = 4; off < 64; off <<= 1)
#pragma unroll
    for (int k = 0; k < 16; k++) acc[k] += __shfl_xor(acc[k], off, 64);

  // valid dims this lane owns: sub0:16, sub1:16, sub2:8, sub3:0
  const int nv = (sub < 2) ? 16 : (sub == 2 ? 8 : 0);
  float v[16];
  float m = -INFINITY, s = 0.f;
  for (int k = 0; k < nv; k++) {
    v[k] = acc[k] + b[sub * 16 + k];
    m = fmaxf(m, v[k]);
  }
#pragma unroll
  for (int off = 1; off < 4; off <<= 1) m = fmaxf(m, __shfl_xor(m, off, 64));
  for (int k = 0; k < nv; k++) s += __expf(v[k] - m);
#pragma unroll
  for (int off = 1; off < 4; off <<= 1) s += __shfl_xor(s, off, 64);

  if (g == 0 && nv > 0) {
    float lg = m + __logf(s);
    float* op = &out[(long)r * 40 + sub * 16];
#pragma unroll
    for (int q = 0; q < 2; q++) {
      if (q * 8 < nv) {
        float4 o0 = make_float4(v[q * 8 + 0] - lg, v[q * 8 + 1] - lg,
                                v[q * 8 + 2] - lg, v[q * 8 + 3] - lg);
        float4 o1 = make_float4(v[q * 8 + 4] - lg, v[q * 8 + 5] - lg,
                                v[q * 8 + 6] - lg, v[q * 8 + 7] - lg);
        *(float4*)(op + q * 8) = o0;
        *(float4*)(op + q * 8 + 4) = o1;
      }
    }
  }
}

extern "C" void kernel_launch(void* const* d_in, const int* in_sizes, int n_in,
                              void* d_out, int out_size, void* d_ws,
                              size_t ws_size, hipStream_t stream) {
  const int* edge_index = (const int*)d_in[0];
  const float* features = (const float*)d_in[1];
  const float* ew = (const float*)d_in[2];
  const float* W1 = (const float*)d_in[3];
  const float* b1 = (const float*)d_in[4];
  const float* W2 = (const float*)d_in[5];
  const float* b2 = (const float*)d_in[6];
  const float* W3 = (const float*)d_in[7];
  const float* b3 = (const float*)d_in[8];
  float* out = (float*)d_out;
  const int* src = edge_index;
  const int* dst = edge_index + NE;

  // workspace layout
  char* p = (char*)d_ws;
  int2* csr = (int2*)p;              p += (size_t)NE * 8;       // 12.8 MB
  int2* esw = (int2*)p;              p += (size_t)NE * 8;       // 12.8 MB
  int* deg = (int*)p;                p += (size_t)NN * 4;
  int* rowptr = (int*)p;             p += (size_t)NN * 4;
  int* bkcnt = (int*)p;              p += 512 * 4;
  int* bkoff = (int*)p;              p += 512 * 4;
  int* bcur = (int*)p;               p += 512 * 4;
  ushort* wswz = (ushort*)p;         p += (size_t)NSLOT * 512 * 2;  // 78 KB
  ushort* hb = (ushort*)p;           p += (size_t)NN * 64 * 2;  // layer buffers
  ushort* xb = (ushort*)p;           p += (size_t)NN * 64 * 2;

  dim3 blk(256);
  const int gemm_grid = (NN + 63) / 64;
  const int row_grid = (NN + 3) / 4;

  // ---- one-time W fragment swizzle (tiny) ----
  wconv_kernel<<<(NSLOT * 64 + 255) / 256, blk, 0, stream>>>(W1, W2, W3, wswz);

  // ---- CSR build v3 (by dst): no global per-edge atomics, coalesced scatter
  hipMemsetAsync(bkcnt, 0, NBUK * sizeof(int), stream);
  histB_kernel<<<(NE + HCHUNK - 1) / HCHUNK, blk, 0, stream>>>(dst, bkcnt);
  scan_bkoff_kernel<<<1, 64, 0, stream>>>(bkcnt, bkoff, bcur);
  bucket_scatter_kernel<<<(NE + CHUNK - 1) / CHUNK, blk, 0, stream>>>(
      src, dst, ew, bcur, esw, NE);
  finalize_kernel<<<NBUK, blk, 0, stream>>>(bkoff, esw, rowptr, deg, csr);

  // ---- layer 1 ----
  gemm_direct<8, 4, 64, true><<<gemm_grid, blk, 0, stream>>>(features, wswz,
                                                             hb, NN);
  agg64_kernel<true><<<row_grid, blk, 0, stream>>>(rowptr, deg, csr, hb, b1,
                                                   xb, NN);
  // ---- layer 2 ----
  gemm_direct<1, 4, 64, false><<<gemm_grid, blk, 0, stream>>>(
      xb, wswz + (size_t)64 * 512, hb, NN);
  agg64_kernel<true><<<row_grid, blk, 0, stream>>>(rowptr, deg, csr, hb, b2,
                                                   xb, NN);
  // ---- layer 3 ----
  gemm_direct<1, 3, 40, false><<<gemm_grid, blk, 0, stream>>>(
      xb, wswz + (size_t)72 * 512, hb, NN);
  agg_lsm_kernel<<<row_grid, blk, 0, stream>>>(rowptr, deg, csr, hb, b3, out,
                                               NN);
}